// Round 5
// baseline (210.023 us; speedup 1.0000x reference)
//
#include <hip/hip_runtime.h>

typedef unsigned short u16;
typedef __attribute__((ext_vector_type(8))) short short8;
typedef __attribute__((ext_vector_type(4))) float f32x4;

#define X0    (-6.0f)
#define GH    (12.0f / 256.0f)     // grid spacing h = 0.046875
#define LOG2E 1.44269504089f

__device__ __forceinline__ u16 f2bf(float x) {
    union { float f; unsigned int u; } v; v.f = x;
    unsigned int r = (v.u + 0x7fffu + ((v.u >> 16) & 1u)) >> 16;
    return (u16)r;
}
__device__ __forceinline__ unsigned int pk(u16 a, u16 b) {
    return (unsigned int)a | ((unsigned int)b << 16);
}
__device__ __forceinline__ uint4 cvt8u(float4 lo, float4 hi) {
    return make_uint4(pk(f2bf(lo.x), f2bf(lo.y)), pk(f2bf(lo.z), f2bf(lo.w)),
                      pk(f2bf(hi.x), f2bf(hi.y)), pk(f2bf(hi.z), f2bf(hi.w)));
}
__device__ __forceinline__ void glds16(const float* g, const float* l) {
    __builtin_amdgcn_global_load_lds(
        (const __attribute__((address_space(1))) void*)g,
        (__attribute__((address_space(3))) void*)l, 16, 0, 0);
}

// K1: Hf[v][j] += sum_s value[v][s] * W_cic[s][j].
// A = value fp32 (64 v-rows x 32 s), staged via global_load_lds with 16B
// xor-swizzle; B = CIC weights built in-register from (bin,frac) LDS LUT.
// M=64(v) N=256(j) per block, K-chunk=128 (32-way k-split). 1024 blocks.
__global__ __launch_bounds__(256, 2) void hbin_kernel(
    const float* __restrict__ key, const float* __restrict__ value,
    float* __restrict__ Hf)
{
    __shared__ float Vt[64 * 32];    // 8 KB, [row][32 floats], 16B-chunk swizzled
    __shared__ int   jl[128];
    __shared__ float fl[128];

    const int tid   = threadIdx.x;
    const int v0    = blockIdx.x << 6;    // 0..448
    const int bz    = blockIdx.y;         // b*32 + ks
    const int b     = bz >> 5;
    const int ks    = bz & 31;
    const int kbase = ks << 7;            // 128-wide s chunk
    const int lane  = tid & 63;
    const int wave  = tid >> 6;
    const int wv    = (wave & 1) << 5;    // 0,32 (m)
    const int wj    = (wave >> 1) << 7;   // 0,128 (n)
    const int m15   = lane & 15;
    const int kq    = lane >> 4;

    if (tid < 128) {
        float k = key[b * 4096 + kbase + tid];
        float u = (k - X0) * (256.0f / 12.0f);
        int j = (int)floorf(u);
        j = j < 0 ? 0 : (j > 254 ? 254 : j);
        float f = u - (float)j;
        f = f < 0.0f ? 0.0f : (f > 1.0f ? 1.0f : f);
        jl[tid] = j; fl[tid] = f;
    }

    f32x4 acc[2][8];
    for (int i = 0; i < 2; ++i)
        for (int j = 0; j < 8; ++j)
            acc[i][j] = (f32x4){0.f, 0.f, 0.f, 0.f};

    // staging geometry: round q covers rows [q*32, q*32+32), thread -> row
    // tid>>3, chunk tid&7; source chunk xor-swizzled by row&7.
    const int srow = tid >> 3;                    // 0..31
    const int scs  = (tid & 7) ^ (srow & 7);      // swizzled 16B chunk
    const float* gsrc = value + (size_t)(b * 512 + v0) * 4096 + kbase;

    for (int kk = 0; kk < 4; ++kk) {
        __syncthreads();     // prev-iter LDS reads done (also covers jl/fl once)
        #pragma unroll
        for (int q = 0; q < 2; ++q) {
            int row = (q << 5) + srow;
            glds16(gsrc + (size_t)row * 4096 + (kk << 5) + scs * 4,
                   Vt + (row << 5) + ((tid & 7) << 2));
        }
        __syncthreads();     // compiler emits vmcnt(0) drain here

        // A fragments: value fp32 -> bf16, un-swizzle on read (2-way free)
        union U { short8 s; uint4 u; } af[2];
        #pragma unroll
        for (int mi = 0; mi < 2; ++mi) {
            int m = wv + mi * 16 + m15;
            int c0 = ((2 * kq)     ^ (m & 7)) << 2;
            int c1 = ((2 * kq + 1) ^ (m & 7)) << 2;
            float4 lo = *(const float4*)(Vt + (m << 5) + c0);
            float4 hi = *(const float4*)(Vt + (m << 5) + c1);
            af[mi].u = cvt8u(lo, hi);
        }

        // B fragments: W[s][J], s = kk*32 + kq*8 + i, J = wj + ni*16 + m15
        int   js[8]; float fs[8], os[8];
        #pragma unroll
        for (int i = 0; i < 8; ++i) {
            int sl = (kk << 5) + (kq << 3) + i;
            js[i] = jl[sl]; fs[i] = fl[sl]; os[i] = 1.0f - fs[i];
        }
        #pragma unroll
        for (int ni = 0; ni < 8; ++ni) {
            int J = wj + ni * 16 + m15;
            float w[8];
            #pragma unroll
            for (int i = 0; i < 8; ++i)
                w[i] = (js[i] == J) ? os[i] : ((js[i] + 1 == J) ? fs[i] : 0.0f);
            union U bf;
            bf.u = cvt8u(make_float4(w[0], w[1], w[2], w[3]),
                         make_float4(w[4], w[5], w[6], w[7]));
            for (int mi = 0; mi < 2; ++mi)
                acc[mi][ni] = __builtin_amdgcn_mfma_f32_16x16x32_bf16(
                    af[mi].s, bf.s, acc[mi][ni], 0, 0, 0);
        }
    }

    #pragma unroll
    for (int mi = 0; mi < 2; ++mi)
        #pragma unroll
        for (int ni = 0; ni < 8; ++ni) {
            float* base = Hf + (size_t)(b * 512 + v0 + wv + mi * 16 + (kq << 2)) * 256
                             + wj + ni * 16 + m15;
            #pragma unroll
            for (int r = 0; r < 4; ++r)
                unsafeAtomicAdd(base + (size_t)r * 256, acc[mi][ni][r]);
        }
}

// K2: out[b][t][v] = sum_k G(q_t, x_k) * H[v][k].  Register-direct A from
// L2-resident Hf (fp32 -> bf16 at frag), Gaussian B on the fly, dwordx4 stores.
__global__ __launch_bounds__(256) void gemm_kernel(
    const float* __restrict__ query, const float* __restrict__ log_scale,
    const float* __restrict__ Hf, float* __restrict__ out)
{
    const int tid  = threadIdx.x;
    const int v0   = blockIdx.x << 7;
    const int t0   = blockIdx.y << 7;
    const int b    = blockIdx.z;
    const int lane = tid & 63;
    const int wave = tid >> 6;
    const int wv   = (wave & 1) << 6;
    const int wt   = (wave >> 1) << 6;
    const int m15  = lane & 15;
    const int kq   = lane >> 4;

    const float c2 = -0.5f * LOG2E * exp2f(-2.0f * LOG2E * log_scale[0]);
    float q[4];
    for (int ni = 0; ni < 4; ++ni)
        q[ni] = query[b * 4096 + t0 + wt + ni * 16 + m15];

    const float* hp[4];
    for (int i = 0; i < 4; ++i)
        hp[i] = Hf + (size_t)(b * 512 + v0 + wv + i * 16 + m15) * 256 + kq * 8;

    f32x4 acc[4][4];
    for (int i = 0; i < 4; ++i)
        for (int j = 0; j < 4; ++j)
            acc[i][j] = (f32x4){0.f, 0.f, 0.f, 0.f};

    union U { short8 s; uint4 u; };
    float4 ab[2][4][2];
    for (int i = 0; i < 4; ++i) {
        ab[0][i][0] = *(const float4*)(hp[i]);
        ab[0][i][1] = *(const float4*)(hp[i] + 4);
    }

    for (int ks = 0; ks < 8; ++ks) {
        const int cur = ks & 1;
        if (ks < 7) {
            const int ko = (ks + 1) << 5;
            for (int i = 0; i < 4; ++i) {
                ab[cur ^ 1][i][0] = *(const float4*)(hp[i] + ko);
                ab[cur ^ 1][i][1] = *(const float4*)(hp[i] + ko + 4);
            }
        }

        U af[4];
        for (int i = 0; i < 4; ++i)
            af[i].u = cvt8u(ab[cur][i][0], ab[cur][i][1]);

        short8 bfr[4];
        const float xb = X0 + GH * (float)((ks << 5) + kq * 8);
        for (int ni = 0; ni < 4; ++ni) {
            short8 e;
            #pragma unroll
            for (int j = 0; j < 8; ++j) {
                float d = q[ni] - (xb + GH * (float)j);
                e[j] = (short)f2bf(exp2f(c2 * d * d));
            }
            bfr[ni] = e;
        }

        for (int mi = 0; mi < 4; ++mi)
            for (int ni = 0; ni < 4; ++ni)
                acc[mi][ni] = __builtin_amdgcn_mfma_f32_16x16x32_bf16(
                    af[mi].s, bfr[ni], acc[mi][ni], 0, 0, 0);
    }

    for (int mi = 0; mi < 4; ++mi)
        for (int ni = 0; ni < 4; ++ni) {
            int t = t0 + wt + ni * 16 + m15;
            float* o = out + (size_t)(b * 4096 + t) * 512
                           + v0 + wv + mi * 16 + (kq << 2);
            *(f32x4*)o = acc[mi][ni];
        }
}

extern "C" void kernel_launch(void* const* d_in, const int* in_sizes, int n_in,
                              void* d_out, int out_size, void* d_ws, size_t ws_size,
                              hipStream_t stream)
{
    const float* query = (const float*)d_in[0];   // [4,4096,1]
    const float* key   = (const float*)d_in[1];   // [4,4096,1]
    const float* value = (const float*)d_in[2];   // [4,512,4096]
    const float* lsc   = (const float*)d_in[3];   // scalar
    float* out = (float*)d_out;                   // [4,4096,512]

    float* Hf = (float*)d_ws;                     // [4][512][256] fp32 = 2 MB

    hipMemsetAsync(Hf, 0, (size_t)4 * 512 * 256 * sizeof(float), stream);
    hbin_kernel<<<dim3(8, 128), 256, 0, stream>>>(key, value, Hf);
    gemm_kernel<<<dim3(4, 32, 4), 256, 0, stream>>>(query, lsc, Hf, out);
}

// Round 6
// 134.227 us; speedup vs baseline: 1.5647x; 1.5647x over previous
//
#include <hip/hip_runtime.h>

typedef unsigned short u16;
typedef __attribute__((ext_vector_type(8))) short short8;
typedef __attribute__((ext_vector_type(4))) float f32x4;

#define X0    (-6.0f)
#define GH    (12.0f / 256.0f)     // grid spacing h = 0.046875
#define LOG2E 1.44269504089f

__device__ __forceinline__ u16 f2bf(float x) {
    union { float f; unsigned int u; } v; v.f = x;
    unsigned int r = (v.u + 0x7fffu + ((v.u >> 16) & 1u)) >> 16;
    return (u16)r;
}
__device__ __forceinline__ unsigned int pk(u16 a, u16 b) {
    return (unsigned int)a | ((unsigned int)b << 16);
}
__device__ __forceinline__ uint4 cvt8u(float4 lo, float4 hi) {
    return make_uint4(pk(f2bf(lo.x), f2bf(lo.y)), pk(f2bf(lo.z), f2bf(lo.w)),
                      pk(f2bf(hi.x), f2bf(hi.y)), pk(f2bf(hi.z), f2bf(hi.w)));
}
__device__ __forceinline__ void glds16(const float* g, const float* l) {
    __builtin_amdgcn_global_load_lds(
        (const __attribute__((address_space(1))) void*)g,
        (__attribute__((address_space(3))) void*)l, 16, 0, 0);
}

// K1: Hpart[b][ks][v][j] = sum_{s in chunk} value[v][s] * W_cic[s][j].
// M=32 v-rows/block, N=256 j, K-chunk=512 s. A staged via glds (16B swizzle,
// r5-verified); B = CIC weights built in-register from (bin,frac) LDS LUT.
// NO atomics: each (b,ks) owns a private fp32 partial plane.
__global__ __launch_bounds__(256) void hpart_kernel(
    const float* __restrict__ key, const float* __restrict__ value,
    float* __restrict__ Hpart)
{
    __shared__ float Vt[32 * 32];    // 4 KB, [row][32 f32], 16B-chunk swizzled
    __shared__ int   jl[512];
    __shared__ float fl[512];

    const int tid   = threadIdx.x;
    const int v0    = blockIdx.x << 5;    // 0..480
    const int b     = blockIdx.y;
    const int ks    = blockIdx.z;
    const int kbase = ks << 9;            // 512-wide s chunk
    const int lane  = tid & 63;
    const int wave  = tid >> 6;
    const int wj    = wave << 6;          // wave owns 64 j
    const int m15   = lane & 15;
    const int kq    = lane >> 4;

    #pragma unroll
    for (int r = 0; r < 2; ++r) {
        int s = tid + (r << 8);
        float k = key[b * 4096 + kbase + s];
        float u = (k - X0) * (256.0f / 12.0f);
        int j = (int)floorf(u);
        j = j < 0 ? 0 : (j > 254 ? 254 : j);
        float f = u - (float)j;
        f = f < 0.0f ? 0.0f : (f > 1.0f ? 1.0f : f);
        jl[s] = j; fl[s] = f;
    }

    f32x4 acc[2][4];
    for (int i = 0; i < 2; ++i)
        for (int j = 0; j < 4; ++j)
            acc[i][j] = (f32x4){0.f, 0.f, 0.f, 0.f};

    const int srow = tid >> 3;                   // 0..31
    const int scs  = (tid & 7) ^ (srow & 7);     // swizzled 16B chunk
    const float* gsrc = value + (size_t)(b * 512 + v0) * 4096 + kbase;
    float* ldst = Vt + (srow << 5) + ((tid & 7) << 2);

    for (int kk = 0; kk < 16; ++kk) {
        __syncthreads();     // prev-iter LDS reads done (covers LUT once)
        glds16(gsrc + (size_t)srow * 4096 + (kk << 5) + scs * 4, ldst);
        __syncthreads();     // vmcnt drain

        union U { short8 s; uint4 u; } af[2];
        #pragma unroll
        for (int mi = 0; mi < 2; ++mi) {
            int m  = mi * 16 + m15;
            int c0 = ((2 * kq)     ^ (m & 7)) << 2;
            int c1 = ((2 * kq + 1) ^ (m & 7)) << 2;
            float4 lo = *(const float4*)(Vt + (m << 5) + c0);
            float4 hi = *(const float4*)(Vt + (m << 5) + c1);
            af[mi].u = cvt8u(lo, hi);
        }

        int   js[8]; float fs[8], os[8];
        #pragma unroll
        for (int i = 0; i < 8; ++i) {
            int sl = (kk << 5) + (kq << 3) + i;
            js[i] = jl[sl]; fs[i] = fl[sl]; os[i] = 1.0f - fs[i];
        }
        #pragma unroll
        for (int ni = 0; ni < 4; ++ni) {
            int J = wj + ni * 16 + m15;
            float w[8];
            #pragma unroll
            for (int i = 0; i < 8; ++i)
                w[i] = (js[i] == J) ? os[i] : ((js[i] + 1 == J) ? fs[i] : 0.0f);
            union U bf;
            bf.u = cvt8u(make_float4(w[0], w[1], w[2], w[3]),
                         make_float4(w[4], w[5], w[6], w[7]));
            for (int mi = 0; mi < 2; ++mi)
                acc[mi][ni] = __builtin_amdgcn_mfma_f32_16x16x32_bf16(
                    af[mi].s, bf.s, acc[mi][ni], 0, 0, 0);
        }
    }

    // private-plane epilogue: plain stores, no atomics
    #pragma unroll
    for (int mi = 0; mi < 2; ++mi)
        #pragma unroll
        for (int ni = 0; ni < 4; ++ni) {
            #pragma unroll
            for (int r = 0; r < 4; ++r) {
                int v = v0 + mi * 16 + (kq << 2) + r;      // row = quad*4+reg
                Hpart[((size_t)(b * 8 + ks) * 512 + v) * 256
                      + wj + ni * 16 + m15] = acc[mi][ni][r];
            }
        }
}

// K2: Hbf[b][v][j] = bf16( sum_{ks<8} Hpart[b][ks][v][j] ). Streaming.
__global__ __launch_bounds__(256) void hred_kernel(
    const float* __restrict__ Hpart, u16* __restrict__ Hbf)
{
    const int gid  = blockIdx.x * 256 + threadIdx.x;   // 0..65535
    const int b    = gid >> 14;
    const size_t off8 = (size_t)(gid & 16383) * 8;
    float4 s0 = make_float4(0.f, 0.f, 0.f, 0.f);
    float4 s1 = make_float4(0.f, 0.f, 0.f, 0.f);
    #pragma unroll
    for (int ks = 0; ks < 8; ++ks) {
        const float* p = Hpart + (size_t)(b * 8 + ks) * 131072 + off8;
        float4 a = *(const float4*)p;
        float4 c = *(const float4*)(p + 4);
        s0.x += a.x; s0.y += a.y; s0.z += a.z; s0.w += a.w;
        s1.x += c.x; s1.y += c.y; s1.z += c.z; s1.w += c.w;
    }
    *(uint4*)(Hbf + (size_t)b * 131072 + off8) = cvt8u(s0, s1);
}

// K3: out[b][t][v] = sum_k G(q_t, x_k) * H[v][k].
// Whole H-tile (128 v x 256 k bf16) staged ONCE -> single barrier, then
// 8 barrier-free MFMA steps with on-the-fly Gaussian B-fragments. (r3-verified)
__global__ __launch_bounds__(256) void gemm_kernel(
    const float* __restrict__ query, const float* __restrict__ log_scale,
    const u16* __restrict__ Hbf, float* __restrict__ out)
{
    extern __shared__ u16 Hl[];        // 128 rows x 264 stride = 67584 B

    const int tid  = threadIdx.x;
    const int v0   = blockIdx.x << 7;
    const int t0   = blockIdx.y << 7;
    const int b    = blockIdx.z;
    const int lane = tid & 63;
    const int wave = tid >> 6;
    const int wv   = (wave & 1) << 6;
    const int wt   = (wave >> 1) << 6;
    const int m15  = lane & 15;
    const int kq   = lane >> 4;

    const float c2 = -0.5f * LOG2E * exp2f(-2.0f * LOG2E * log_scale[0]);
    float q[4];
    for (int ni = 0; ni < 4; ++ni)
        q[ni] = query[b * 4096 + t0 + wt + ni * 16 + m15];

    // stage: thread = (row = tid>>1, half = tid&1); contiguous 256 B per thread
    {
        const int row = tid >> 1, half = tid & 1;
        const u16* src = Hbf + (size_t)(b * 512 + v0 + row) * 256 + half * 128;
        u16* dst = Hl + row * 264 + half * 128;
        #pragma unroll
        for (int i = 0; i < 16; ++i)
            *(uint4*)(dst + i * 8) = *(const uint4*)(src + i * 8);
    }
    __syncthreads();

    f32x4 acc[4][4];
    for (int i = 0; i < 4; ++i)
        for (int j = 0; j < 4; ++j)
            acc[i][j] = (f32x4){0.f, 0.f, 0.f, 0.f};

    for (int ks = 0; ks < 8; ++ks) {
        const int k0 = ks << 5;
        short8 af[4];
        for (int i = 0; i < 4; ++i)
            af[i] = *(const short8*)(Hl + (wv + i * 16 + m15) * 264 + k0 + kq * 8);

        short8 bfr[4];
        const float xb = X0 + GH * (float)(k0 + kq * 8);
        for (int ni = 0; ni < 4; ++ni) {
            short8 e;
            #pragma unroll
            for (int j = 0; j < 8; ++j) {
                float d = q[ni] - (xb + GH * (float)j);
                e[j] = (short)f2bf(exp2f(c2 * d * d));
            }
            bfr[ni] = e;
        }
        for (int mi = 0; mi < 4; ++mi)
            for (int ni = 0; ni < 4; ++ni)
                acc[mi][ni] = __builtin_amdgcn_mfma_f32_16x16x32_bf16(
                    af[mi], bfr[ni], acc[mi][ni], 0, 0, 0);
    }

    for (int mi = 0; mi < 4; ++mi)
        for (int ni = 0; ni < 4; ++ni) {
            int t = t0 + wt + ni * 16 + m15;
            float* o = out + (size_t)(b * 4096 + t) * 512
                           + v0 + wv + mi * 16 + (kq << 2);
            *(f32x4*)o = acc[mi][ni];
        }
}

extern "C" void kernel_launch(void* const* d_in, const int* in_sizes, int n_in,
                              void* d_out, int out_size, void* d_ws, size_t ws_size,
                              hipStream_t stream)
{
    const float* query = (const float*)d_in[0];   // [4,4096,1]
    const float* key   = (const float*)d_in[1];   // [4,4096,1]
    const float* value = (const float*)d_in[2];   // [4,512,4096]
    const float* lsc   = (const float*)d_in[3];   // scalar
    float* out = (float*)d_out;                   // [4,4096,512]

    float* Hpart = (float*)d_ws;                                  // 16 MB
    u16*   Hbf   = (u16*)((char*)d_ws + (size_t)16 * 1024 * 1024); // 1 MB

    hpart_kernel<<<dim3(16, 4, 8), 256, 0, stream>>>(key, value, Hpart);
    hred_kernel<<<256, 256, 0, stream>>>(Hpart, Hbf);
    gemm_kernel<<<dim3(4, 32, 4), 256, 128 * 264 * 2, stream>>>(query, lsc, Hbf, out);
}